// Round 5
// baseline (374.664 us; speedup 1.0000x reference)
//
#include <hip/hip_runtime.h>
#include <math.h>

// QLSTM: 12-qubit statevector sim, 16 steps x 4 gates x 64 samples.
// ONE workgroup per sample (64 WGs x 1024 threads): sim s = tid>>8 handles
// gate s on 256 threads (stid = tid&255, 16 amps/thread). The h/c recurrence
// is WG-local -> no atomics/rendezvous at all. 16 waves/CU = 4 waves/SIMD.
// Qubit q <-> bit (11-q) of the flat amp index.
// Key algebra: pre-CNOT state = (x)_{q} [Rot_q . RX(th_q)|0>] — a product of
// 12 complex 2-vectors; each thread builds its 16 amps by a cmul tree.
// LDS swizzle p = i ^ ((i>>4)&15) (conflict profile verified in r2-r4).

__device__ __forceinline__ int swz(int i) { return i ^ ((i >> 4) & 15); }

__device__ __forceinline__ float ftanh(float x) {
    x = fminf(fmaxf(x, -15.f), 15.f);
    const float e = __expf(2.f * x);
    return (e - 1.f) / (e + 1.f);
}
__device__ __forceinline__ float fsigm(float x) { return 1.f / (1.f + __expf(-x)); }

// Apply 4 Rot gates (strides 8,4,2,1 in j) to 16 register-resident amps.
__device__ __forceinline__ void rot4(float ar[16], float ai[16],
                                     const float* __restrict__ m4) {
#pragma unroll
    for (int k = 0; k < 4; ++k) {
        const float g0r = m4[k*8+0], g0i = m4[k*8+1];
        const float g1r = m4[k*8+2], g1i = m4[k*8+3];
        const float g2r = m4[k*8+4], g2i = m4[k*8+5];
        const float g3r = m4[k*8+6], g3i = m4[k*8+7];
        const int vs = 8 >> k;
#pragma unroll
        for (int p = 0; p < 8; ++p) {
            const int lowm = vs - 1;
            const int j0 = ((p & ~lowm) << 1) | (p & lowm);
            const int j1 = j0 | vs;
            const float a0r = ar[j0], a0i = ai[j0];
            const float a1r = ar[j1], a1i = ai[j1];
            ar[j0] = g0r*a0r - g0i*a0i + g1r*a1r - g1i*a1i;
            ai[j0] = g0r*a0i + g0i*a0r + g1r*a1i + g1i*a1r;
            ar[j1] = g2r*a0r - g2i*a0i + g3r*a1r - g3i*a1i;
            ai[j1] = g2r*a0i + g2i*a0r + g3r*a1i + g3i*a1r;
        }
    }
}

__global__ __launch_bounds__(1024, 1)
void qlstm_all(const float* __restrict__ inputs,
               const float* __restrict__ wf, const float* __restrict__ wi,
               const float* __restrict__ wu, const float* __restrict__ wo,
               const float* __restrict__ fW, const float* __restrict__ fb,
               const float* __restrict__ iW, const float* __restrict__ ib,
               const float* __restrict__ uW, const float* __restrict__ ub,
               const float* __restrict__ oW, const float* __restrict__ ob,
               float* __restrict__ out)        // 4096 + 256 + 256
{
    __shared__ float2 buf[4][4096];     // 128 KB: one statevector per gate-sim
    __shared__ float rotm[4][192];      // 4 gate types x 24 gates x 8
    __shared__ float Wsh[4][48];        // head weights (H=4 x N=12)
    __shared__ float bsh[4][4];
    __shared__ float zredw[4][4][12];   // (sim, wave-in-sim, qubit)
    __shared__ float acts[16];          // (gate, unit)

    const int tid = threadIdx.x;
    const int b = blockIdx.x;
    const int s = tid >> 8;             // gate-sim 0..3 (f,i,u,o)
    const int stid = tid & 255;

    // ---- one-time staging: Rot matrices, head weights ----
    if (tid < 128) {
        const int g = tid >> 5, k = tid & 31;        // k = l*12 + qubit
        if (k < 24) {
            const float* wsel = (g == 0) ? wf : (g == 1) ? wi : (g == 2) ? wu : wo;
            const float phi = wsel[k*3+0], th = wsel[k*3+1], om = wsel[k*3+2];
            float ct, sth; __sincosf(0.5f * th, &sth, &ct);
            float ca, sa;  __sincosf(0.5f * (phi + om), &sa, &ca);
            float cb, sb;  __sincosf(0.5f * (phi - om), &sb, &cb);
            float* m = rotm[g] + k * 8;
            m[0] =  ca * ct;  m[1] = -sa * ct;
            m[2] = -cb * sth; m[3] = -sb * sth;
            m[4] =  cb * sth; m[5] = -sb * sth;
            m[6] =  ca * ct;  m[7] =  sa * ct;
        }
    } else if (tid < 384) {
        const int idx = tid - 128, g = idx >> 6, r = idx & 63;
        if (r < 48) {
            const float* Wsel = (g == 0) ? fW : (g == 1) ? iW : (g == 2) ? uW : oW;
            Wsh[g][r] = Wsel[r];
        }
    } else if (tid < 400) {
        const int idx = tid - 384, g = idx >> 2, u = idx & 3;
        const float* bsel = (g == 0) ? fb : (g == 1) ? ib : (g == 2) ? ub : ob;
        bsh[g][u] = bsel[u];
    }
    __syncthreads();

    float c4[4] = {0.f, 0.f, 0.f, 0.f};
    float h4[4] = {0.f, 0.f, 0.f, 0.f};

    const float* rg = rotm[s];
    const int aBase = stid << 4, aMsk = stid & 15;
    const int bBase = ((stid >> 4) << 8) | (stid & 15);
    const int cBase = stid ^ ((stid >> 4) & 15);
    // GF(2)-linear parts of the CNOT perms for this thread's 16-amp block
    const int sA0 = aBase ^ (aBase >> 1);       // sigma0(A^j)=sA0^c0(j)
    const int sA1 = aBase ^ (aBase >> 2);       // sigma1(A^j)=sA1^c1(j)

    for (int t = 0; t < 16; ++t) {
        float ar[16], ai[16];

        // ==== A: product state = (x)_q w_q, w_q = Rot_q . RX|0> ====
        {
            // U over qubits 0..7 (bits of stid), angles from x_t
            float Ur = 1.f, Ui = 0.f;
#pragma unroll
            for (int q = 0; q < 8; ++q) {
                float sn, cs;
                __sincosf(0.5f * inputs[t * 512 + b * 8 + q], &sn, &cs);
                const float* m = rg + q * 8;
                const int bit = (stid >> (7 - q)) & 1;
                // w = R.(cos, -i sin): row {0,1} picked by bit
                const float wr = bit ? (m[4]*cs + m[7]*sn) : (m[0]*cs + m[3]*sn);
                const float wim = bit ? (m[5]*cs - m[6]*sn) : (m[1]*cs - m[2]*sn);
                const float nr = Ur*wr - Ui*wim;
                const float ni = Ur*wim + Ui*wr;
                Ur = nr; Ui = ni;
            }
            // v_q for qubits 8..11, angles from h
            float v0r[2], v0i[2], v1r[2], v1i[2], v2r[2], v2i[2], v3r[2], v3i[2];
#pragma unroll
            for (int qq = 0; qq < 4; ++qq) {
                float sn, cs; __sincosf(0.5f * h4[qq], &sn, &cs);
                const float* m = rg + (8 + qq) * 8;
                const float w0r = m[0]*cs + m[3]*sn, w0i = m[1]*cs - m[2]*sn;
                const float w1r = m[4]*cs + m[7]*sn, w1i = m[5]*cs - m[6]*sn;
                if (qq == 0) { v0r[0]=w0r; v0i[0]=w0i; v0r[1]=w1r; v0i[1]=w1i; }
                if (qq == 1) { v1r[0]=w0r; v1i[0]=w0i; v1r[1]=w1r; v1i[1]=w1i; }
                if (qq == 2) { v2r[0]=w0r; v2i[0]=w0i; v2r[1]=w1r; v2i[1]=w1i; }
                if (qq == 3) { v3r[0]=w0r; v3i[0]=w0i; v3r[1]=w1r; v3i[1]=w1i; }
            }
            // trees: p01 = (U*v0) (x) v1 ; p23 = v2 (x) v3
            float p01r[4], p01i[4], p23r[4], p23i[4];
#pragma unroll
            for (int a = 0; a < 2; ++a) {
                const float uvr = Ur*v0r[a] - Ui*v0i[a];
                const float uvi = Ur*v0i[a] + Ui*v0r[a];
#pragma unroll
                for (int d = 0; d < 2; ++d) {
                    p01r[a*2+d] = uvr*v1r[d] - uvi*v1i[d];
                    p01i[a*2+d] = uvr*v1i[d] + uvi*v1r[d];
                    p23r[a*2+d] = v2r[a]*v3r[d] - v2i[a]*v3i[d];
                    p23i[a*2+d] = v2r[a]*v3i[d] + v2i[a]*v3r[d];
                }
            }
#pragma unroll
            for (int j = 0; j < 16; ++j) {
                const int hi = j >> 2, lo = j & 3;
                ar[j] = p01r[hi]*p23r[lo] - p01i[hi]*p23i[lo];
                ai[j] = p01r[hi]*p23i[lo] + p01i[hi]*p23r[lo];
            }
#pragma unroll
            for (int j = 0; j < 16; ++j)
                buf[s][aBase | (j ^ aMsk)] = make_float2(ar[j], ai[j]);
        }
        __syncthreads();   // S1: full pre-CNOT state in buf[s]

        // ==== sigma0 gather (CNOT ring L0) + Rot L1 q8..11, in place ====
#pragma unroll
        for (int j = 0; j < 16; ++j) {
            const int cj = (j ^ (j >> 1)) ^ ((j & 1) ? 0xC00 : 0);
            const float2 v = buf[s][swz(sA0 ^ cj)];
            ar[j] = v.x; ai[j] = v.y;
        }
        __syncthreads();   // S2: all gathers done before overwrite
        rot4(ar, ai, rg + 160);
#pragma unroll
        for (int j = 0; j < 16; ++j)
            buf[s][aBase | (j ^ aMsk)] = make_float2(ar[j], ai[j]);
        __builtin_amdgcn_wave_barrier();   // B1 reads within this wave's quarter

        // ==== B1: Rot L1 q4..7 (wave-local 256-blocks) ====
#pragma unroll
        for (int j = 0; j < 16; ++j) {
            const float2 v = buf[s][bBase ^ (j << 4) ^ j];
            ar[j] = v.x; ai[j] = v.y;
        }
        rot4(ar, ai, rg + 128);
#pragma unroll
        for (int j = 0; j < 16; ++j)
            buf[s][bBase ^ (j << 4) ^ j] = make_float2(ar[j], ai[j]);
        __syncthreads();   // S3: C1 reads cross-wave

        // ==== C1: Rot L1 q0..3 (stride 256), thread-local in place ====
#pragma unroll
        for (int j = 0; j < 16; ++j) {
            const float2 v = buf[s][cBase + (j << 8)];
            ar[j] = v.x; ai[j] = v.y;
        }
        rot4(ar, ai, rg + 96);
#pragma unroll
        for (int j = 0; j < 16; ++j)
            buf[s][cBase + (j << 8)] = make_float2(ar[j], ai[j]);
        __syncthreads();   // S4: sigma1 gather reads everything

        // ==== Expvals: CNOT ring L1 fused as gather sigma1 ====
        float S = 0.f, z8 = 0.f, z9 = 0.f, z10 = 0.f, z11 = 0.f;
#pragma unroll
        for (int j = 0; j < 16; ++j) {
            const int cj = (j ^ (j >> 2)) ^ ((j & 2) ? 0xA00 : 0) ^ ((j & 1) ? 0x500 : 0);
            const float2 v = buf[s][swz(sA1 ^ cj)];
            const float p = v.x * v.x + v.y * v.y;
            S += p;
            z8  += (j & 8) ? -p : p;
            z9  += (j & 4) ? -p : p;
            z10 += (j & 2) ? -p : p;
            z11 += (j & 1) ? -p : p;
        }
        float zq[12];
#pragma unroll
        for (int q = 0; q < 8; ++q)
            zq[q] = ((stid >> (7 - q)) & 1) ? -S : S;
        zq[8] = z8; zq[9] = z9; zq[10] = z10; zq[11] = z11;

        const int lane = tid & 63, wv = (tid >> 6) & 3;
#pragma unroll
        for (int q = 0; q < 12; ++q) {
            float v = zq[q];
#pragma unroll
            for (int off = 32; off > 0; off >>= 1) v += __shfl_down(v, off);
            if (lane == 0) zredw[s][wv][q] = v;
        }
        __syncthreads();   // S5: all sims' partial z in LDS

        // ==== heads: 16 threads = (gate, unit) ====
        if (tid < 16) {
            const int gg = tid >> 2, u = tid & 3;
            float acc = bsh[gg][u];
#pragma unroll
            for (int q = 0; q < 12; ++q) {
                const float zs = zredw[gg][0][q] + zredw[gg][1][q]
                               + zredw[gg][2][q] + zredw[gg][3][q];
                acc += Wsh[gg][u * 12 + q] * zs;
            }
            acts[tid] = (gg == 2) ? ftanh(acc) : fsigm(acc);
        }
        __syncthreads();   // S6: acts visible

        // ==== recurrence, replicated per thread (deterministic) ====
#pragma unroll
        for (int u = 0; u < 4; ++u) {
            const float f_ = acts[u], i_ = acts[4 + u],
                        g_ = acts[8 + u], o_ = acts[12 + u];
            c4[u] = f_ * c4[u] + i_ * g_;
            h4[u] = o_ * ftanh(c4[u]);
        }
        if (tid < 4) out[t * 256 + b * 4 + tid] = h4[tid];
    }

    if (tid < 4) {
        out[4096 + b * 4 + tid] = h4[tid];   // hx
        out[4352 + b * 4 + tid] = c4[tid];   // cx
    }
}

extern "C" void kernel_launch(void* const* d_in, const int* in_sizes, int n_in,
                              void* d_out, int out_size, void* d_ws, size_t ws_size,
                              hipStream_t stream) {
    (void)in_sizes; (void)n_in; (void)out_size; (void)d_ws; (void)ws_size;
    const float* inputs = (const float*)d_in[0];
    const float* wf = (const float*)d_in[1];
    const float* wi = (const float*)d_in[2];
    const float* wu = (const float*)d_in[3];
    const float* wo = (const float*)d_in[4];
    const float* fW = (const float*)d_in[5];
    const float* fb = (const float*)d_in[6];
    const float* iW = (const float*)d_in[7];
    const float* ib = (const float*)d_in[8];
    const float* uW = (const float*)d_in[9];
    const float* ub = (const float*)d_in[10];
    const float* oW = (const float*)d_in[11];
    const float* ob = (const float*)d_in[12];
    float* out = (float*)d_out;

    qlstm_all<<<dim3(64), dim3(1024), 0, stream>>>(
        inputs, wf, wi, wu, wo, fW, fb, iW, ib, uW, ub, oW, ob, out);
}

// Round 6
// 219.402 us; speedup vs baseline: 1.7077x; 1.7077x over previous
//
#include <hip/hip_runtime.h>
#include <math.h>

#define AGENT __HIP_MEMORY_SCOPE_AGENT

// QLSTM: 12-qubit statevector sim, 16 steps x 4 gates x 64 samples.
// 256 WGs x 512 threads: WG = (gate g, sample b), 8 amps/thread
// (2 waves/SIMD on all 256 CUs). Qubit q <-> bit (11-q) of amp index.
// Pre-CNOT state = product of 12 two-vectors (validated r5 algebra).
// L1 rots: 3 LDS sweeps, each = rot3 on local qubits + 1 DPP-paired qubit.
// LDS layout: LDS[sb(i)] = amp(i), sb(i) = i ^ ((i>>4)&15) (XOR-linear;
// every sweep pattern rank-checked to 4 lanes/bank-pair = b64 optimum).
// Cross-WG recurrence: r4's validated relaxed-spin rendezvous.

__device__ __forceinline__ float ftanh(float x) {
    x = fminf(fmaxf(x, -15.f), 15.f);
    const float e = __expf(2.f * x);
    return (e - 1.f) / (e + 1.f);
}
__device__ __forceinline__ float fsigm(float x) { return 1.f / (1.f + __expf(-x)); }
__device__ __forceinline__ float gld(const float* p) {
    return __hip_atomic_load(p, __ATOMIC_RELAXED, AGENT);
}

template<int CTRL>
__device__ __forceinline__ float dppf(float x) {   // quad_perm lane swap (VALU)
    return __int_as_float(__builtin_amdgcn_update_dpp(
        0, __float_as_int(x), CTRL, 0xF, 0xF, true));
}

// rot on the DPP-paired qubit: own-row coef (por,poi), partner coef (ppr,ppi)
template<int CTRL>
__device__ __forceinline__ void dpprot(float ar[8], float ai[8],
                                       float por, float poi, float ppr, float ppi) {
#pragma unroll
    for (int j = 0; j < 8; ++j) {
        const float qr = dppf<CTRL>(ar[j]);
        const float qi = dppf<CTRL>(ai[j]);
        const float nr = por*ar[j] - poi*ai[j] + ppr*qr - ppi*qi;
        const float ni = por*ai[j] + poi*ar[j] + ppr*qi + ppi*qr;
        ar[j] = nr; ai[j] = ni;
    }
}

// 3 Rot gates on local qubits: strides 4,2,1 over 8 register amps.
__device__ __forceinline__ void rot3(float ar[8], float ai[8],
                                     const float* __restrict__ g3) {
    float gm[24];
#pragma unroll
    for (int k = 0; k < 6; ++k) ((float4*)gm)[k] = ((const float4*)g3)[k];
#pragma unroll
    for (int k = 0; k < 3; ++k) {
        const float m0=gm[k*8+0], m1=gm[k*8+1], m2=gm[k*8+2], m3=gm[k*8+3];
        const float m4=gm[k*8+4], m5=gm[k*8+5], m6=gm[k*8+6], m7=gm[k*8+7];
        const int vs = 4 >> k;
#pragma unroll
        for (int p = 0; p < 4; ++p) {
            const int lowm = vs - 1;
            const int j0 = ((p & ~lowm) << 1) | (p & lowm);
            const int j1 = j0 | vs;
            const float a0r = ar[j0], a0i = ai[j0];
            const float a1r = ar[j1], a1i = ai[j1];
            ar[j0] = m0*a0r - m1*a0i + m2*a1r - m3*a1i;
            ai[j0] = m0*a0i + m1*a0r + m2*a1i + m3*a1r;
            ar[j1] = m4*a0r - m5*a0i + m6*a1r - m7*a1i;
            ai[j1] = m4*a0i + m5*a0r + m6*a1i + m7*a1r;
        }
    }
}

#define CMUL(dr, di, xr, xi, yr, yi) \
    do { dr = (xr)*(yr) - (xi)*(yi); di = (xr)*(yi) + (xi)*(yr); } while (0)

__global__ __launch_bounds__(512, 2)
void qlstm_fused(const float* __restrict__ inputs,
                 const float* __restrict__ wf, const float* __restrict__ wi,
                 const float* __restrict__ wu, const float* __restrict__ wo,
                 const float* __restrict__ fW, const float* __restrict__ fb,
                 const float* __restrict__ iW, const float* __restrict__ ib,
                 const float* __restrict__ uW, const float* __restrict__ ub,
                 const float* __restrict__ oW, const float* __restrict__ ob,
                 float* __restrict__ gact,     // ws: [2][4][64][4]
                 unsigned* __restrict__ ctr,   // ws: [64][16], memset 0
                 float* __restrict__ out)      // 4096 + 256 + 256
{
    __shared__ __align__(16) float2 buf0[4096], buf1[4096];
    __shared__ __align__(16) float rotm[192];   // 24 gates x 8 (this WG's type)
    __shared__ __align__(16) float4 wtab[8];    // x-dep 2-vectors q0..7
    __shared__ __align__(16) float4 Ttab[8];    // head fold, j-part
    __shared__ float zred[8][4];

    const int tid = threadIdx.x;
    const int b = blockIdx.x & 63;
    const int g = blockIdx.x >> 6;

    const float* wsel = (g == 0) ? wf : (g == 1) ? wi : (g == 2) ? wu : wo;
    const float* Wsel = (g == 0) ? fW : (g == 1) ? iW : (g == 2) ? uW : oW;
    const float* bsel = (g == 0) ? fb : (g == 1) ? ib : (g == 2) ? ub : ob;

    // ---- one-time staging ----
    if (tid < 24) {                              // Rot matrices (t-invariant)
        const int k = tid;                       // l*12 + qubit
        const float phi = wsel[k*3+0], th = wsel[k*3+1], om = wsel[k*3+2];
        float ct, sth; __sincosf(0.5f * th, &sth, &ct);
        float ca, sa;  __sincosf(0.5f * (phi + om), &sa, &ca);
        float cb, sb2; __sincosf(0.5f * (phi - om), &sb2, &cb);
        float* m = rotm + k * 8;
        m[0] =  ca * ct;  m[1] = -sa * ct;
        m[2] = -cb * sth; m[3] = -sb2 * sth;
        m[4] =  cb * sth; m[5] = -sb2 * sth;
        m[6] =  ca * ct;  m[7] =  sa * ct;
    }
    if (tid >= 32 && tid < 40) {                 // T_u[j] over q9..11 signs
        const int j = tid - 32;
        const float s9  = (j & 4) ? -1.f : 1.f;
        const float s10 = (j & 2) ? -1.f : 1.f;
        const float s11 = (j & 1) ? -1.f : 1.f;
        Ttab[j] = make_float4(
            Wsel[ 9]*s9 + Wsel[10]*s10 + Wsel[11]*s11,
            Wsel[21]*s9 + Wsel[22]*s10 + Wsel[23]*s11,
            Wsel[33]*s9 + Wsel[34]*s10 + Wsel[35]*s11,
            Wsel[45]*s9 + Wsel[46]*s10 + Wsel[47]*s11);
    }
    // K_u(stid) over q0..8 signs (loop-invariant, per-thread regs)
    float K0 = 0.f, K1 = 0.f, K2 = 0.f, K3 = 0.f;
#pragma unroll
    for (int q = 0; q < 9; ++q) {
        const float sgn = ((tid >> (8 - q)) & 1) ? -1.f : 1.f;
        K0 += sgn * Wsel[q]; K1 += sgn * Wsel[12 + q];
        K2 += sgn * Wsel[24 + q]; K3 += sgn * Wsel[36 + q];
    }
    const float bu = (tid < 4) ? bsel[tid] : 0.f;
    __syncthreads();

    // ---- per-thread address constants (all t-invariant) ----
    const int cA  = (tid << 3) ^ ((tid >> 1) & 15);           // sb(stid*8 | j) = cA^j
    const int sA0 = (tid << 3) ^ (tid << 2);
    const int c0  = sA0 ^ ((sA0 >> 4) & 15);                  // sb(sigma0 thread part)
    const int P2  = ((tid >> 5) << 8) | (((tid >> 1) & 1) << 4)
                  | (((tid >> 4) & 1) << 3) | (((tid >> 3) & 1) << 2)
                  | (((tid >> 2) & 1) << 1) | (tid & 1);
    const int c2  = P2 ^ ((P2 >> 4) & 15);
    const int P3  = ((tid & 1) << 8) | (tid >> 1);
    const int c3  = P3 ^ ((P3 >> 4) & 15);
    const int sA1 = (tid << 3) ^ (tid << 1);
    const int cS1 = sA1 ^ ((sA1 >> 4) & 15);
    const int k0c[8] = {0, 0xC01, 3, 0xC02, 6, 0xC07, 5, 0xC04};  // sb(sigma0 j-part)
    const int k1c[8] = {0, 0x501, 0xA02, 0xF03, 5, 0x504, 0xA07, 0xF06};

    float c40=0.f,c41=0.f,c42=0.f,c43=0.f, h40=0.f,h41=0.f,h42=0.f,h43=0.f;

    for (int t = 0; t < 16; ++t) {
        // ---- x-dep 2-vectors (tids 0..7) + rendezvous spin (tid 64) ----
        if (tid < 8) {
            float sn, cs; __sincosf(0.5f * inputs[t*512 + b*8 + tid], &sn, &cs);
            const float* m = rotm + tid * 8;     // L0 gate q=tid
            wtab[tid] = make_float4(m[0]*cs + m[3]*sn, m[1]*cs - m[2]*sn,
                                    m[4]*cs + m[7]*sn, m[5]*cs - m[6]*sn);
        }
        if (t > 0 && tid == 64) {
            while (__hip_atomic_load(&ctr[b*16 + (t-1)], __ATOMIC_RELAXED, AGENT) < 4u)
                __builtin_amdgcn_s_sleep(2);
            __threadfence();
        }
        __syncthreads();                         // B0

        // ---- recurrence (replicated per thread; deterministic) ----
        if (t > 0) {
            const float* ga = gact + ((t-1)&1)*1024 + b*4;
            const float f0=gld(ga+0),   f1=gld(ga+1),   f2=gld(ga+2),   f3=gld(ga+3);
            const float i0=gld(ga+256), i1=gld(ga+257), i2=gld(ga+258), i3=gld(ga+259);
            const float u0=gld(ga+512), u1=gld(ga+513), u2=gld(ga+514), u3=gld(ga+515);
            const float o0=gld(ga+768), o1=gld(ga+769), o2=gld(ga+770), o3=gld(ga+771);
            c40 = f0*c40 + i0*u0;  h40 = o0*ftanh(c40);
            c41 = f1*c41 + i1*u1;  h41 = o1*ftanh(c41);
            c42 = f2*c42 + i2*u2;  h42 = o2*ftanh(c42);
            c43 = f3*c43 + i3*u3;  h43 = o3*ftanh(c43);
            if (g == 0) {
                if (tid == 0) out[(t-1)*256 + b*4 + 0] = h40;
                if (tid == 1) out[(t-1)*256 + b*4 + 1] = h41;
                if (tid == 2) out[(t-1)*256 + b*4 + 2] = h42;
                if (tid == 3) out[(t-1)*256 + b*4 + 3] = h43;
            }
        }

        // ---- A: product-state amps (8 per thread) -> buf0 ----
        {
            // h-dep rows q8..11
            float s8,c8s, s9,c9s, s10,c10s, s11,c11s;
            __sincosf(0.5f*h40, &s8,  &c8s);
            __sincosf(0.5f*h41, &s9,  &c9s);
            __sincosf(0.5f*h42, &s10, &c10s);
            __sincosf(0.5f*h43, &s11, &c11s);
            const int b8 = tid & 1;              // q8 <-> stid bit0
            const float* m8 = rotm + 64;
            const float w8r = b8 ? (m8[4]*c8s + m8[7]*s8) : (m8[0]*c8s + m8[3]*s8);
            const float w8i = b8 ? (m8[5]*c8s - m8[6]*s8) : (m8[1]*c8s - m8[2]*s8);
            const float* m9 = rotm + 72;
            const float v9r0 = m9[0]*c9s + m9[3]*s9,  v9i0 = m9[1]*c9s - m9[2]*s9;
            const float v9r1 = m9[4]*c9s + m9[7]*s9,  v9i1 = m9[5]*c9s - m9[6]*s9;
            const float* mA = rotm + 80;
            const float vAr0 = mA[0]*c10s + mA[3]*s10, vAi0 = mA[1]*c10s - mA[2]*s10;
            const float vAr1 = mA[4]*c10s + mA[7]*s10, vAi1 = mA[5]*c10s - mA[6]*s10;
            const float* mB = rotm + 88;
            const float vBr0 = mB[0]*c11s + mB[3]*s11, vBi0 = mB[1]*c11s - mB[2]*s11;
            const float vBr1 = mB[4]*c11s + mB[7]*s11, vBi1 = mB[5]*c11s - mB[6]*s11;

            // U-chain over q0..7 rows from wtab (tree)
            const float* wt = (const float*)wtab;
            float rr[8], ri[8];
#pragma unroll
            for (int q = 0; q < 8; ++q) {
                const int bit = (tid >> (8 - q)) & 1;
                const float2 w = *(const float2*)(wt + q*4 + bit*2);
                rr[q] = w.x; ri[q] = w.y;
            }
            float t0r,t0i,t1r,t1i,t2r,t2i,t3r,t3i, x0r,x0i,x1r,x1i, Ur,Ui, U8r,U8i;
            CMUL(t0r,t0i, rr[0],ri[0], rr[1],ri[1]);
            CMUL(t1r,t1i, rr[2],ri[2], rr[3],ri[3]);
            CMUL(t2r,t2i, rr[4],ri[4], rr[5],ri[5]);
            CMUL(t3r,t3i, rr[6],ri[6], rr[7],ri[7]);
            CMUL(x0r,x0i, t0r,t0i, t1r,t1i);
            CMUL(x1r,x1i, t2r,t2i, t3r,t3i);
            CMUL(Ur,Ui, x0r,x0i, x1r,x1i);
            CMUL(U8r,U8i, Ur,Ui, w8r,w8i);

            float e0r,e0i,e1r,e1i;               // U8 * v9[a]
            CMUL(e0r,e0i, U8r,U8i, v9r0,v9i0);
            CMUL(e1r,e1i, U8r,U8i, v9r1,v9i1);
            float q0r,q0i,q1r,q1i,q2r,q2i,q3r,q3i;   // * v10[d]
            CMUL(q0r,q0i, e0r,e0i, vAr0,vAi0);
            CMUL(q1r,q1i, e0r,e0i, vAr1,vAi1);
            CMUL(q2r,q2i, e1r,e1i, vAr0,vAi0);
            CMUL(q3r,q3i, e1r,e1i, vAr1,vAi1);
            float ar[8], ai[8];                  // * v11[j&1]
            CMUL(ar[0],ai[0], q0r,q0i, vBr0,vBi0);
            CMUL(ar[1],ai[1], q0r,q0i, vBr1,vBi1);
            CMUL(ar[2],ai[2], q1r,q1i, vBr0,vBi0);
            CMUL(ar[3],ai[3], q1r,q1i, vBr1,vBi1);
            CMUL(ar[4],ai[4], q2r,q2i, vBr0,vBi0);
            CMUL(ar[5],ai[5], q2r,q2i, vBr1,vBi1);
            CMUL(ar[6],ai[6], q3r,q3i, vBr0,vBi0);
            CMUL(ar[7],ai[7], q3r,q3i, vBr1,vBi1);
#pragma unroll
            for (int j = 0; j < 8; ++j)
                buf0[cA ^ j] = make_float2(ar[j], ai[j]);
        }
        __syncthreads();                         // B1

        // ---- sweep1: sigma0 gather + Rot L1 {q8 DPP, q9..11 local} -> buf1 ----
        {
            float ar[8], ai[8];
#pragma unroll
            for (int j = 0; j < 8; ++j) {
                const float2 v = buf0[c0 ^ k0c[j]];
                ar[j] = v.x; ai[j] = v.y;
            }
            const int be = tid & 1;
            const float4 row = *(const float4*)(rotm + 160 + (be << 2));
            const float por = be ? row.z : row.x, poi = be ? row.w : row.y;
            const float ppr = be ? row.x : row.z, ppi = be ? row.y : row.w;
            dpprot<0xB1>(ar, ai, por, poi, ppr, ppi);        // xor1
            rot3(ar, ai, rotm + 168);                        // q9,q10,q11
#pragma unroll
            for (int j = 0; j < 8; ++j)
                buf1[cA ^ j] = make_float2(ar[j], ai[j]);
        }
        __syncthreads();                         // B2

        // ---- sweep2: Rot L1 {q7 DPP, q4..6 local}, in place in buf1 ----
        {
            float ar[8], ai[8]; int adr[8];
#pragma unroll
            for (int j = 0; j < 8; ++j) {
                adr[j] = c2 ^ ((j << 5) ^ (j << 1));
                const float2 v = buf1[adr[j]];
                ar[j] = v.x; ai[j] = v.y;
            }
            const int be = (tid >> 1) & 1;
            const float4 row = *(const float4*)(rotm + 152 + (be << 2));
            const float por = be ? row.z : row.x, poi = be ? row.w : row.y;
            const float ppr = be ? row.x : row.z, ppi = be ? row.y : row.w;
            dpprot<0x4E>(ar, ai, por, poi, ppr, ppi);        // xor2
            rot3(ar, ai, rotm + 128);                        // q4,q5,q6
#pragma unroll
            for (int j = 0; j < 8; ++j)
                buf1[adr[j]] = make_float2(ar[j], ai[j]);
        }
        __syncthreads();                         // B3

        // ---- sweep3: Rot L1 {q3 DPP, q0..2 local}, in place in buf1 ----
        {
            float ar[8], ai[8]; int adr[8];
#pragma unroll
            for (int j = 0; j < 8; ++j) {
                adr[j] = c3 ^ (j << 9);
                const float2 v = buf1[adr[j]];
                ar[j] = v.x; ai[j] = v.y;
            }
            const int be = tid & 1;
            const float4 row = *(const float4*)(rotm + 120 + (be << 2));
            const float por = be ? row.z : row.x, poi = be ? row.w : row.y;
            const float ppr = be ? row.x : row.z, ppi = be ? row.y : row.w;
            dpprot<0xB1>(ar, ai, por, poi, ppr, ppi);        // xor1
            rot3(ar, ai, rotm + 96);                         // q0,q1,q2
#pragma unroll
            for (int j = 0; j < 8; ++j)
                buf1[adr[j]] = make_float2(ar[j], ai[j]);
        }
        __syncthreads();                         // B4

        // ---- expvals: sigma1 gather; head folded (K,S,T) ----
        float S = 0.f, d0 = 0.f, d1 = 0.f, d2 = 0.f, d3 = 0.f;
#pragma unroll
        for (int j = 0; j < 8; ++j) {
            const float2 v = buf1[cS1 ^ k1c[j]];
            const float p = v.x*v.x + v.y*v.y;
            S += p;
            const float4 tv = Ttab[j];
            d0 += p*tv.x; d1 += p*tv.y; d2 += p*tv.z; d3 += p*tv.w;
        }
        float p0 = K0*S + d0, p1 = K1*S + d1, p2 = K2*S + d2, p3 = K3*S + d3;
#pragma unroll
        for (int off = 32; off > 0; off >>= 1) {
            p0 += __shfl_down(p0, off);
            p1 += __shfl_down(p1, off);
            p2 += __shfl_down(p2, off);
            p3 += __shfl_down(p3, off);
        }
        if ((tid & 63) == 0) {
            const int wv = tid >> 6;
            zred[wv][0] = p0; zred[wv][1] = p1; zred[wv][2] = p2; zred[wv][3] = p3;
        }
        __syncthreads();                         // B5

        if (tid < 4) {
            float tot = 0.f;
#pragma unroll
            for (int w = 0; w < 8; ++w) tot += zred[w][tid];
            const float acc = bu + tot;
            const float act = (g == 2) ? ftanh(acc) : fsigm(acc);
            __hip_atomic_store(&gact[(t&1)*1024 + g*256 + b*4 + tid], act,
                               __ATOMIC_RELAXED, AGENT);
        }
        if (tid == 0)
            __hip_atomic_fetch_add(&ctr[b*16 + t], 1u, __ATOMIC_RELEASE, AGENT);
    }

    // ---- finalize: consume step-15 activations (g==0 WGs only) ----
    if (g == 0) {
        if (tid == 64) {
            while (__hip_atomic_load(&ctr[b*16 + 15], __ATOMIC_RELAXED, AGENT) < 4u)
                __builtin_amdgcn_s_sleep(2);
            __threadfence();
        }
        __syncthreads();
        if (tid < 4) {
            const float* ga = gact + 1024 + b*4;     // slot 15&1 = 1
#pragma unroll
            for (int u = 0; u < 4; ++u) if (tid == u) {
                const float f_ = gld(ga + u),       i_ = gld(ga + 256 + u);
                const float u_ = gld(ga + 512 + u), o_ = gld(ga + 768 + u);
                const float cp = (u == 0) ? c40 : (u == 1) ? c41 : (u == 2) ? c42 : c43;
                const float cn = f_*cp + i_*u_;
                const float hn = o_*ftanh(cn);
                out[3840 + b*4 + u] = hn;   // outputs[15]
                out[4096 + b*4 + u] = hn;   // hx
                out[4352 + b*4 + u] = cn;   // cx
            }
        }
    }
}

extern "C" void kernel_launch(void* const* d_in, const int* in_sizes, int n_in,
                              void* d_out, int out_size, void* d_ws, size_t ws_size,
                              hipStream_t stream) {
    (void)in_sizes; (void)n_in; (void)out_size; (void)ws_size;
    const float* inputs = (const float*)d_in[0];
    const float* wf = (const float*)d_in[1];
    const float* wi = (const float*)d_in[2];
    const float* wu = (const float*)d_in[3];
    const float* wo = (const float*)d_in[4];
    const float* fW = (const float*)d_in[5];
    const float* fb = (const float*)d_in[6];
    const float* iW = (const float*)d_in[7];
    const float* ib = (const float*)d_in[8];
    const float* uW = (const float*)d_in[9];
    const float* ub = (const float*)d_in[10];
    const float* oW = (const float*)d_in[11];
    const float* ob = (const float*)d_in[12];
    float* out = (float*)d_out;
    unsigned* ctr = (unsigned*)d_ws;               // [64][16]
    float* gact = (float*)d_ws + 1024;             // [2][4][64][4]

    hipMemsetAsync(ctr, 0, 1024 * sizeof(unsigned), stream);

    void* args[] = { (void*)&inputs, (void*)&wf, (void*)&wi, (void*)&wu, (void*)&wo,
                     (void*)&fW, (void*)&fb, (void*)&iW, (void*)&ib,
                     (void*)&uW, (void*)&ub, (void*)&oW, (void*)&ob,
                     (void*)&gact, (void*)&ctr, (void*)&out };
    hipError_t err = hipLaunchCooperativeKernel((const void*)qlstm_fused,
                                                dim3(256), dim3(512),
                                                args, 0, stream);
    if (err != hipSuccess) {
        // Fallback: plain launch; 256 WGs (1/CU) co-resident on idle device.
        qlstm_fused<<<dim3(256), dim3(512), 0, stream>>>(
            inputs, wf, wi, wu, wo, fW, fb, iW, ib, uW, ub, oW, ob,
            gact, ctr, out);
    }
}

// Round 7
// 168.187 us; speedup vs baseline: 2.2277x; 1.3045x over previous
//
#include <hip/hip_runtime.h>
#include <math.h>

#define AGENT __HIP_MEMORY_SCOPE_AGENT

// QLSTM: 12-qubit statevector sim, 16 steps x 4 gates x 64 samples.
// 256 WGs x 512 threads: WG = (gate g, sample b), 8 amps/thread.
// Qubit q <-> bit (11-q) of the flat amp index.
//
// Pipeline per step (all algebra GF(2)-verified):
//   build: amps = w'(sigma0(idx)) directly in regs (sigma0 folded into the
//          product-state factor tree; no LDS pass, no gather).
//   gates: q9,q10,q11 local rot3; q8,q7 DPP quad_perm; q3 shfl_xor(32);
//          exchange1 (LDS) -> q4,q5,q6 local rot3;
//          exchange2 (LDS) -> q0,q1,q2 local rot3.
//   measure: sigma1 eliminated -- <Z_m> = sum |amp|^2 * (-1)^parity(idx&R_m),
//          R_m = rows of sigma1^-1 (closed-form suffix-XOR chains, verified).
//          Head matvec folded into per-slot Q constants.
// Cross-WG recurrence: r4/r6-validated relaxed-spin rendezvous via ws.

__device__ __forceinline__ float ftanh(float x) {
    x = fminf(fmaxf(x, -15.f), 15.f);
    const float e = __expf(2.f * x);
    return (e - 1.f) / (e + 1.f);
}
__device__ __forceinline__ float fsigm(float x) { return 1.f / (1.f + __expf(-x)); }
__device__ __forceinline__ float gld(const float* p) {
    return __hip_atomic_load(p, __ATOMIC_RELAXED, AGENT);
}

#define CMUL(dr, di, xr, xi, yr, yi) \
    do { dr = (xr)*(yr) - (xi)*(yi); di = (xr)*(yi) + (xi)*(yr); } while (0)

template<int CTRL>
__device__ __forceinline__ float dppf(float x) {   // quad_perm lane swap (VALU)
    return __int_as_float(__builtin_amdgcn_update_dpp(
        0, __float_as_int(x), CTRL, 0xF, 0xF, true));
}

template<int CTRL>
__device__ __forceinline__ void dpprot(float ar[8], float ai[8],
                                       float por, float poi, float ppr, float ppi) {
#pragma unroll
    for (int j = 0; j < 8; ++j) {
        const float qr = dppf<CTRL>(ar[j]);
        const float qi = dppf<CTRL>(ai[j]);
        const float nr = por*ar[j] - poi*ai[j] + ppr*qr - ppi*qi;
        const float ni = por*ai[j] + poi*ar[j] + ppr*qi + ppi*qr;
        ar[j] = nr; ai[j] = ni;
    }
}

__device__ __forceinline__ void shflrot32(float ar[8], float ai[8],
                                          float por, float poi, float ppr, float ppi) {
#pragma unroll
    for (int j = 0; j < 8; ++j) {
        const float qr = __shfl_xor(ar[j], 32);
        const float qi = __shfl_xor(ai[j], 32);
        const float nr = por*ar[j] - poi*ai[j] + ppr*qr - ppi*qi;
        const float ni = por*ai[j] + poi*ar[j] + ppr*qi + ppi*qr;
        ar[j] = nr; ai[j] = ni;
    }
}

// 3 Rot gates on slot-local qubits: strides 4,2,1 over 8 register amps.
__device__ __forceinline__ void rot3(float ar[8], float ai[8],
                                     const float* __restrict__ g3) {
    float gm[24];
#pragma unroll
    for (int k = 0; k < 6; ++k) ((float4*)gm)[k] = ((const float4*)g3)[k];
#pragma unroll
    for (int k = 0; k < 3; ++k) {
        const float m0=gm[k*8+0], m1=gm[k*8+1], m2=gm[k*8+2], m3=gm[k*8+3];
        const float m4=gm[k*8+4], m5=gm[k*8+5], m6=gm[k*8+6], m7=gm[k*8+7];
        const int vs = 4 >> k;
#pragma unroll
        for (int p = 0; p < 4; ++p) {
            const int lowm = vs - 1;
            const int j0 = ((p & ~lowm) << 1) | (p & lowm);
            const int j1 = j0 | vs;
            const float a0r = ar[j0], a0i = ai[j0];
            const float a1r = ar[j1], a1i = ai[j1];
            ar[j0] = m0*a0r - m1*a0i + m2*a1r - m3*a1i;
            ai[j0] = m0*a0i + m1*a0r + m2*a1i + m3*a1r;
            ar[j1] = m4*a0r - m5*a0i + m6*a1r - m7*a1i;
            ai[j1] = m4*a0i + m5*a0r + m6*a1i + m7*a1r;
        }
    }
}

__global__ __launch_bounds__(512, 2)
void qlstm_fused(const float* __restrict__ inputs,
                 const float* __restrict__ wf, const float* __restrict__ wi,
                 const float* __restrict__ wu, const float* __restrict__ wo,
                 const float* __restrict__ fW, const float* __restrict__ fb,
                 const float* __restrict__ iW, const float* __restrict__ ib,
                 const float* __restrict__ uW, const float* __restrict__ ub,
                 const float* __restrict__ oW, const float* __restrict__ ob,
                 float* __restrict__ gact,     // ws: [2][4][64][4]
                 unsigned* __restrict__ ctr,   // ws: [64][16], memset 0
                 float* __restrict__ out)      // 4096 + 256 + 256
{
    __shared__ float2 bufA[4096], bufB[4096];
    __shared__ __align__(16) float rotm[192];   // 24 gates x 8 (this WG's type)
    __shared__ __align__(16) float4 wtab[12];   // per-qubit 2-vectors w'_q
    __shared__ float Wsh[48];
    __shared__ float zred[8][4];

    const int tid = threadIdx.x;
    const int b = blockIdx.x & 63;
    const int g = blockIdx.x >> 6;
    const int l = tid & 63, w = tid >> 6;

    const float* wsel = (g == 0) ? wf : (g == 1) ? wi : (g == 2) ? wu : wo;
    const float* Wsel = (g == 0) ? fW : (g == 1) ? iW : (g == 2) ? uW : oW;
    const float* bsel = (g == 0) ? fb : (g == 1) ? ib : (g == 2) ? ub : ob;

    // ---- one-time staging ----
    if (tid < 24) {                              // Rot matrices (t-invariant)
        const int k = tid;                       // l*12 + qubit
        const float phi = wsel[k*3+0], th = wsel[k*3+1], om = wsel[k*3+2];
        float ct, sth; __sincosf(0.5f * th, &sth, &ct);
        float ca, sa;  __sincosf(0.5f * (phi + om), &sa, &ca);
        float cb, sb2; __sincosf(0.5f * (phi - om), &sb2, &cb);
        float* m = rotm + k * 8;
        m[0] =  ca * ct;  m[1] = -sa * ct;
        m[2] = -cb * sth; m[3] = -sb2 * sth;
        m[4] =  cb * sth; m[5] = -sb2 * sth;
        m[6] =  ca * ct;  m[7] =  sa * ct;
    }
    if (tid < 48) Wsh[tid] = Wsel[tid];
    const float bu = (tid < 4) ? bsel[tid] : 0.f;
    __syncthreads();

    // ---- Q precompute: fold measurement signs + head matvec per amp slot ----
    // sign masks R_p (p = bit position = 11 - measured qubit), rows of sigma1^-1
    const int MSK[12] = {0x555,0xAAA,0x554,0xAA8,0x550,0xAA0,
                         0x540,0xA80,0x500,0xA00,0x155,0x2AA};
    // true amp index held at final layout: idx = s<<9 | l5<<8 | w<<5 | l4l3<<3 | l2l1l0
    const int qbase = ((l >> 5) << 8) | (w << 5) | (((l >> 3) & 3) << 3) | (l & 7);
    float4 Qv[8];
#pragma unroll
    for (int s = 0; s < 8; ++s) {
        float q0 = 0.f, q1 = 0.f, q2 = 0.f, q3 = 0.f;
        const int idx = qbase | (s << 9);
#pragma unroll
        for (int p = 0; p < 12; ++p) {
            const float sgn = (__popc(idx & MSK[p]) & 1) ? -1.f : 1.f;
            const int m = 11 - p;
            q0 += sgn * Wsh[m];
            q1 += sgn * Wsh[12 + m];
            q2 += sgn * Wsh[24 + m];
            q3 += sgn * Wsh[36 + m];
        }
        Qv[s] = make_float4(q0, q1, q2, q3);
    }

    // ---- t-invariant constants ----
    // X0 = sigma0(tid<<3): per-thread fixed part of x = sigma0(idx)
    const int X0 = (tid << 3) ^ (tid << 2);
    int bitq[7];                                 // x bits 9..3 -> qubits 2..8
#pragma unroll
    for (int qq = 0; qq < 7; ++qq) bitq[qq] = (X0 >> (9 - qq)) & 1;
    const int b11 = (tid >> 8) & 1;              // x bit11 (qubit 0)
    const int b10 = ((tid >> 7) & 1) ^ b11;      // x bit10 (qubit 1)
    const int lx  = tid & 1;                     // x bit2 high part (qubit 9 sel)
    // exchange addressing, swizzle SW(a) = a ^ ((a>>3)&15) (4 lanes/bank-pair)
    const int wbase = (tid << 3) ^ (tid & 15);   // write: SW(tid<<3|s) = wbase^s
    const int rb1 = ((w << 9) | (((l >> 5) & 1) << 8) |
                     (((l >> 3) & 3) << 3) | (l & 7)) ^ ((l >> 3) & 3);
    const int rb2 = ((l << 3) | w) ^ (l & 15);
    const int be8 = l & 1, be7 = (l >> 1) & 1, be3 = (l >> 5) & 1;

    float c_ = 0.f, h_ = 0.f;                    // live in lanes 0..3 (unit = tid)

    for (int t = 0; t < 16; ++t) {
        // ---- wave1: x-dependent 2-vectors q0..7 ----
        if (tid >= 64 && tid < 72) {
            const int q = tid - 64;
            float sn, cs; __sincosf(0.5f * inputs[t*512 + b*8 + q], &sn, &cs);
            const float* m = rotm + q * 8;
            wtab[q] = make_float4(m[0]*cs + m[3]*sn, m[1]*cs - m[2]*sn,
                                  m[4]*cs + m[7]*sn, m[5]*cs - m[6]*sn);
        }
        // ---- lanes 0..3: rendezvous spin + recurrence + h rows q8..11 ----
        if (tid < 4) {
            if (t > 0) {
                while (__hip_atomic_load(&ctr[b*16 + (t-1)],
                                         __ATOMIC_RELAXED, AGENT) < 4u)
                    __builtin_amdgcn_s_sleep(2);
                __threadfence();
                const float* ga = gact + ((t-1)&1)*1024 + b*4 + tid;
                const float f_ = gld(ga),       i_ = gld(ga + 256);
                const float u_ = gld(ga + 512), o_ = gld(ga + 768);
                c_ = f_*c_ + i_*u_;
                h_ = o_*ftanh(c_);
                if (g == 0) out[(t-1)*256 + b*4 + tid] = h_;
            }
            float sn, cs; __sincosf(0.5f * h_, &sn, &cs);
            const float* m = rotm + (8 + tid) * 8;
            wtab[8 + tid] = make_float4(m[0]*cs + m[3]*sn, m[1]*cs - m[2]*sn,
                                        m[4]*cs + m[7]*sn, m[5]*cs - m[6]*sn);
        }
        __syncthreads();   // B0

        // ==== build: amps = w'(sigma0(idx)), 8 per thread, in regs ====
        const float* wf4 = (const float*)wtab;
        float Pr, Pi;                             // prefix: qubits 2..8
        {
            const float2 f0 = *(const float2*)(wf4 + 2*4 + bitq[0]*2);
            Pr = f0.x; Pi = f0.y;
#pragma unroll
            for (int qq = 1; qq < 7; ++qq) {
                const float2 f = *(const float2*)(wf4 + (2+qq)*4 + bitq[qq]*2);
                float nr, ni; CMUL(nr, ni, Pr, Pi, f.x, f.y);
                Pr = nr; Pi = ni;
            }
        }
        const float4 R0 = wtab[0], R1 = wtab[1];
        const float4 R9 = wtab[9], RA = wtab[10], RB = wtab[11];
        // qubits 0,1: bits 11,10 flip together for odd slots (0xC00 term)
        const float v0sr = b11 ? R0.z : R0.x, v0si = b11 ? R0.w : R0.y;
        const float v0or = b11 ? R0.x : R0.z, v0oi = b11 ? R0.y : R0.w;
        const float v1sr = b10 ? R1.z : R1.x, v1si = b10 ? R1.w : R1.y;
        const float v1or = b10 ? R1.x : R1.z, v1oi = b10 ? R1.y : R1.w;
        float Er, Ei, Og, Oh;
        CMUL(Er, Ei, v0sr, v0si, v1sr, v1si);
        CMUL(Og, Oh, v0or, v0oi, v1or, v1oi);
        float PEr, PEi, POr, POi;
        CMUL(PEr, PEi, Pr, Pi, Er, Ei);
        CMUL(POr, POi, Pr, Pi, Og, Oh);
        // qubits 9,10,11: bits 2,1,0 of x = (lx<<2) ^ gray(s)
        const float w9lr = lx ? R9.z : R9.x, w9li = lx ? R9.w : R9.y;
        const float w9hr = lx ? R9.x : R9.z, w9hi = lx ? R9.y : R9.w;
        float m0r,m0i, m1r,m1i, m2r,m2i, m3r,m3i;
        CMUL(m0r,m0i, w9lr,w9li, RA.x,RA.y);
        CMUL(m1r,m1i, w9lr,w9li, RA.z,RA.w);
        CMUL(m2r,m2i, w9hr,w9hi, RA.x,RA.y);
        CMUL(m3r,m3i, w9hr,w9hi, RA.z,RA.w);
        float ttr[8], tti[8];
        CMUL(ttr[0],tti[0], m0r,m0i, RB.x,RB.y);
        CMUL(ttr[1],tti[1], m0r,m0i, RB.z,RB.w);
        CMUL(ttr[2],tti[2], m1r,m1i, RB.x,RB.y);
        CMUL(ttr[3],tti[3], m1r,m1i, RB.z,RB.w);
        CMUL(ttr[4],tti[4], m2r,m2i, RB.x,RB.y);
        CMUL(ttr[5],tti[5], m2r,m2i, RB.z,RB.w);
        CMUL(ttr[6],tti[6], m3r,m3i, RB.x,RB.y);
        CMUL(ttr[7],tti[7], m3r,m3i, RB.z,RB.w);
        float ar[8], ai[8];                      // slot s: gray(s) selects tt
        CMUL(ar[0],ai[0], PEr,PEi, ttr[0],tti[0]);
        CMUL(ar[1],ai[1], POr,POi, ttr[1],tti[1]);
        CMUL(ar[2],ai[2], PEr,PEi, ttr[3],tti[3]);
        CMUL(ar[3],ai[3], POr,POi, ttr[2],tti[2]);
        CMUL(ar[4],ai[4], PEr,PEi, ttr[6],tti[6]);
        CMUL(ar[5],ai[5], POr,POi, ttr[7],tti[7]);
        CMUL(ar[6],ai[6], PEr,PEi, ttr[5],tti[5]);
        CMUL(ar[7],ai[7], POr,POi, ttr[4],tti[4]);

        // ==== Rot L1 gates ====
        rot3(ar, ai, rotm + 168);                // q9,q10,q11 (slot bits)
        {                                        // q8: lane bit0, DPP xor1
            const float4 row = *(const float4*)(rotm + 160 + (be8 << 2));
            const float por = be8 ? row.z : row.x, poi = be8 ? row.w : row.y;
            const float ppr = be8 ? row.x : row.z, ppi = be8 ? row.y : row.w;
            dpprot<0xB1>(ar, ai, por, poi, ppr, ppi);
        }
        {                                        // q7: lane bit1, DPP xor2
            const float4 row = *(const float4*)(rotm + 152 + (be7 << 2));
            const float por = be7 ? row.z : row.x, poi = be7 ? row.w : row.y;
            const float ppr = be7 ? row.x : row.z, ppi = be7 ? row.y : row.w;
            dpprot<0x4E>(ar, ai, por, poi, ppr, ppi);
        }
        {                                        // q3: lane bit5, shfl xor32
            const float4 row = *(const float4*)(rotm + 120 + (be3 << 2));
            const float por = be3 ? row.z : row.x, poi = be3 ? row.w : row.y;
            const float ppr = be3 ? row.x : row.z, ppi = be3 ? row.y : row.w;
            shflrot32(ar, ai, por, poi, ppr, ppi);
        }
        // ---- exchange1: slots <-> idx bits 7:5 -> q4,q5,q6 local ----
#pragma unroll
        for (int s = 0; s < 8; ++s)
            bufA[wbase ^ s] = make_float2(ar[s], ai[s]);
        __syncthreads();   // B1
#pragma unroll
        for (int s = 0; s < 8; ++s) {
            const float2 v = bufA[(rb1 | (s << 5)) ^ ((s & 3) << 2)];
            ar[s] = v.x; ai[s] = v.y;
        }
        rot3(ar, ai, rotm + 128);                // q4,q5,q6
        // ---- exchange2: slots <-> idx bits 11:9 -> q0,q1,q2 local ----
#pragma unroll
        for (int s = 0; s < 8; ++s)
            bufB[wbase ^ s] = make_float2(ar[s], ai[s]);
        __syncthreads();   // B2
#pragma unroll
        for (int s = 0; s < 8; ++s) {
            const float2 v = bufB[rb2 | (s << 9)];
            ar[s] = v.x; ai[s] = v.y;
        }
        rot3(ar, ai, rotm + 96);                 // q0,q1,q2

        // ==== measure + folded head ====
        float a0 = 0.f, a1 = 0.f, a2 = 0.f, a3 = 0.f;
#pragma unroll
        for (int s = 0; s < 8; ++s) {
            const float p = ar[s]*ar[s] + ai[s]*ai[s];
            a0 += p * Qv[s].x; a1 += p * Qv[s].y;
            a2 += p * Qv[s].z; a3 += p * Qv[s].w;
        }
#pragma unroll
        for (int off = 32; off > 0; off >>= 1) {
            a0 += __shfl_down(a0, off);
            a1 += __shfl_down(a1, off);
            a2 += __shfl_down(a2, off);
            a3 += __shfl_down(a3, off);
        }
        if (l == 0) {
            zred[w][0] = a0; zred[w][1] = a1; zred[w][2] = a2; zred[w][3] = a3;
        }
        __syncthreads();   // B3
        if (tid < 4) {
            float tot = bu;
#pragma unroll
            for (int wv = 0; wv < 8; ++wv) tot += zred[wv][tid];
            const float act = (g == 2) ? ftanh(tot) : fsigm(tot);
            __hip_atomic_store(&gact[(t&1)*1024 + g*256 + b*4 + tid], act,
                               __ATOMIC_RELAXED, AGENT);
        }
        if (tid == 0)   // release drains the wave's prior stores (lanes 0..3)
            __hip_atomic_fetch_add(&ctr[b*16 + t], 1u, __ATOMIC_RELEASE, AGENT);
    }

    // ==== finalize: consume step-15 activations (g==0, lanes 0..3) ====
    if (g == 0 && tid < 4) {
        while (__hip_atomic_load(&ctr[b*16 + 15], __ATOMIC_RELAXED, AGENT) < 4u)
            __builtin_amdgcn_s_sleep(2);
        __threadfence();
        const float* ga = gact + 1024 + b*4 + tid;       // slot 15&1 = 1
        const float f_ = gld(ga),       i_ = gld(ga + 256);
        const float u_ = gld(ga + 512), o_ = gld(ga + 768);
        const float cn = f_*c_ + i_*u_;
        const float hn = o_*ftanh(cn);
        out[3840 + b*4 + tid] = hn;   // outputs[15]
        out[4096 + b*4 + tid] = hn;   // hx
        out[4352 + b*4 + tid] = cn;   // cx
    }
}

extern "C" void kernel_launch(void* const* d_in, const int* in_sizes, int n_in,
                              void* d_out, int out_size, void* d_ws, size_t ws_size,
                              hipStream_t stream) {
    (void)in_sizes; (void)n_in; (void)out_size; (void)ws_size;
    const float* inputs = (const float*)d_in[0];
    const float* wf = (const float*)d_in[1];
    const float* wi = (const float*)d_in[2];
    const float* wu = (const float*)d_in[3];
    const float* wo = (const float*)d_in[4];
    const float* fW = (const float*)d_in[5];
    const float* fb = (const float*)d_in[6];
    const float* iW = (const float*)d_in[7];
    const float* ib = (const float*)d_in[8];
    const float* uW = (const float*)d_in[9];
    const float* ub = (const float*)d_in[10];
    const float* oW = (const float*)d_in[11];
    const float* ob = (const float*)d_in[12];
    float* out = (float*)d_out;
    unsigned* ctr = (unsigned*)d_ws;               // [64][16]
    float* gact = (float*)d_ws + 1024;             // [2][4][64][4]

    hipMemsetAsync(ctr, 0, 1024 * sizeof(unsigned), stream);

    void* args[] = { (void*)&inputs, (void*)&wf, (void*)&wi, (void*)&wu, (void*)&wo,
                     (void*)&fW, (void*)&fb, (void*)&iW, (void*)&ib,
                     (void*)&uW, (void*)&ub, (void*)&oW, (void*)&ob,
                     (void*)&gact, (void*)&ctr, (void*)&out };
    hipError_t err = hipLaunchCooperativeKernel((const void*)qlstm_fused,
                                                dim3(256), dim3(512),
                                                args, 0, stream);
    if (err != hipSuccess) {
        // Fallback: plain launch; 256 WGs (1/CU) co-resident on idle device.
        qlstm_fused<<<dim3(256), dim3(512), 0, stream>>>(
            inputs, wf, wi, wu, wo, fW, fb, iW, ib, uW, ub, oW, ob,
            gact, ctr, out);
    }
}